// Round 12
// baseline (176.340 us; speedup 1.0000x reference)
//
#include <hip/hip_runtime.h>
#include <math.h>

#define NE 32
#define HID 2880
#define NSTEP 90          // 2880/32 k-steps total
#define TT 64             // tokens per block
#define THREADS 256       // 4 waves; wave wv owns tokens [t0+16*wv, +16)
#define WSB_BYTES (3 * NSTEP * 2 * 64 * 16)   // 552960 B packed W fragments

typedef short bf16x8 __attribute__((ext_vector_type(8)));
typedef float f32x4 __attribute__((ext_vector_type(4)));

union FragU { uint4 q; bf16x8 v; };

// global_load_lds: wave-uniform LDS dest + lane*16; per-lane global src.
#define GLL(gsrc, ldst)                                                        \
  __builtin_amdgcn_global_load_lds(                                            \
      (const __attribute__((address_space(1))) unsigned int*)(gsrc),           \
      (__attribute__((address_space(3))) unsigned int*)(ldst), 16, 0, 0)

// ---------- kernel 0: split W into 3 bf16 limbs packed as B-fragments,
//            and zero the per-token-group arrival counters ------------------
// Fragment (p, s, t): lane l holds 8 bf16 = W_p[t*16 + (l&15)][s*32 + (l>>4)*8 + j]
__global__ void __launch_bounds__(256) wsplit_kernel(
    const float* __restrict__ w, unsigned int* __restrict__ wsB,
    int* __restrict__ cnt, int ntg)
{
  const int gid = blockIdx.x * 256 + threadIdx.x;   // 0..11519
  if (gid < ntg) cnt[gid] = 0;

  const int s  = gid >> 7;
  const int tl = (gid >> 6) & 1;
  const int l  = gid & 63;

  const float* src = w + (size_t)(tl * 16 + (l & 15)) * HID + s * 32 + ((l >> 4) * 8);
  float4 xa = *(const float4*)src;
  float4 xb = *(const float4*)(src + 4);
  float x[8] = {xa.x, xa.y, xa.z, xa.w, xb.x, xb.y, xb.z, xb.w};

  unsigned int u0[8], u1[8], u2[8];
#pragma unroll
  for (int j = 0; j < 8; ++j) {
    unsigned int ux = __float_as_uint(x[j]);
    u0[j] = ux & 0xFFFF0000u;                       // limb0 (truncated bf16)
    float r1 = x[j] - __uint_as_float(u0[j]);       // exact
    u1[j] = __float_as_uint(r1) & 0xFFFF0000u;      // limb1
    float r2 = r1 - __uint_as_float(u1[j]);         // exact
    u2[j] = __float_as_uint(r2);                    // limb2 (trunc on pack)
  }

  uint4* dst = (uint4*)wsB;
  uint4 d;
  d.x = __builtin_amdgcn_perm(u0[1], u0[0], 0x07060302u);
  d.y = __builtin_amdgcn_perm(u0[3], u0[2], 0x07060302u);
  d.z = __builtin_amdgcn_perm(u0[5], u0[4], 0x07060302u);
  d.w = __builtin_amdgcn_perm(u0[7], u0[6], 0x07060302u);
  dst[((0 * NSTEP + s) * 2 + tl) * 64 + l] = d;
  d.x = __builtin_amdgcn_perm(u1[1], u1[0], 0x07060302u);
  d.y = __builtin_amdgcn_perm(u1[3], u1[2], 0x07060302u);
  d.z = __builtin_amdgcn_perm(u1[5], u1[4], 0x07060302u);
  d.w = __builtin_amdgcn_perm(u1[7], u1[6], 0x07060302u);
  dst[((1 * NSTEP + s) * 2 + tl) * 64 + l] = d;
  d.x = __builtin_amdgcn_perm(u2[1], u2[0], 0x07060302u);
  d.y = __builtin_amdgcn_perm(u2[3], u2[2], 0x07060302u);
  d.z = __builtin_amdgcn_perm(u2[5], u2[4], 0x07060302u);
  d.w = __builtin_amdgcn_perm(u2[7], u2[6], 0x07060302u);
  dst[((2 * NSTEP + s) * 2 + tl) * 64 + l] = d;
}

// ---------- kernel 1: MFMA GEMM partials + fused last-arrival topk ---------
// h AND W staged in LDS via GLL (W shared by all 4 waves -> 4x less L2
// traffic, 12 fewer VMEM instrs per chunk). Round-9 drain-barrier schedule.
__global__ void __launch_bounds__(THREADS) router_mfma(
    const float* __restrict__ hs,         // [T][HID]
    const unsigned int* __restrict__ wsB, // packed W fragments
    float* __restrict__ wsp,              // [KQ][T][NE] fp32 partials
    int* __restrict__ cnt,                // [ntg] arrival counters
    const float* __restrict__ bias,
    float* __restrict__ out,              // [T][NE] scores, then [T][4] idx
    int T, int KQ, int ntg)
{
  __shared__ float hbuf[2][4096];   // 2 x 16 KB: [64 rows][16 swizzled 16B slots]
  __shared__ float wbuf[2][3072];   // 2 x 12 KB: 12 fragments x 64 lanes x 16 B
  __shared__ int slast;

  const int tid = threadIdx.x;
  const int wv  = __builtin_amdgcn_readfirstlane(tid >> 6);
  const int l   = tid & 63;
  const int q   = l >> 4;
  const int r15 = l & 15;
  const int tg  = blockIdx.x % ntg;
  const int kq  = blockIdx.x / ntg;
  const int t0  = tg * TT;

  int nsteps, s0;
  if (KQ == 4) { nsteps = (kq == 0) ? 24 : 22; s0 = (kq == 0) ? 0 : (2 + 22 * kq); }
  else         { nsteps = (kq == 0) ? 46 : 44; s0 = (kq == 0) ? 0 : 46; }
  const int nchunk = nsteps >> 1;   // 2 k-steps (64 k) per chunk

  // h staging offsets: phys slot f holds logical slot (f&15)^(row&15) of row f>>4
  int goffH[4];
#pragma unroll
  for (int i = 0; i < 4; ++i) {
    int f = tid + 256 * i;
    int row = f >> 4;
    int G = (f & 15) ^ (row & 15);
    goffH[i] = row * HID + G * 4;   // float offset within chunk
  }
  // W staging offsets (uint4 units, sans k-step term): slot j holds frag
  // f=j>>6 = p*4+sl*2+t, element e=j&63; src idx = ((p*NSTEP+sg0+sl)*2+t)*64+e
  int goffW[3];
#pragma unroll
  for (int i = 0; i < 3; ++i) {
    int j = tid + 256 * i;          // 0..767
    int f = j >> 6, e = j & 63;
    int p = f >> 2, sl = (f >> 1) & 1, t = f & 1;
    goffW[i] = ((p * 2 * NSTEP + sl * 2 + t) * 64 + e);
  }

  const int hrowb = (wv * 16 + r15) * 256;   // row byte base within hbuf

  f32x4 acc0 = {0.f, 0.f, 0.f, 0.f};
  f32x4 acc1 = {0.f, 0.f, 0.f, 0.f};

  const float* hbase = hs + (size_t)t0 * HID + s0 * 32;
  const uint4* wsb4 = (const uint4*)wsB;

  // prologue: stage chunk 0 (h + W)
#pragma unroll
  for (int i = 0; i < 4; ++i)
    GLL(hbase + goffH[i], (char*)&hbuf[0][0] + (tid + 256 * i) * 16);
#pragma unroll
  for (int i = 0; i < 3; ++i)
    GLL(wsb4 + goffW[i] + (size_t)s0 * 128, (char*)&wbuf[0][0] + (tid + 256 * i) * 16);
  __syncthreads();

#pragma clang loop unroll(disable)
  for (int c = 0; c < nchunk; ++c) {
    // issue next chunk's staging (h + W); __syncthreads drains before use
    if (c + 1 < nchunk) {
      const float* hn = hbase + (c + 1) * 64;
      char* hb_n = (char*)&hbuf[(c + 1) & 1][0];
      char* wb_n = (char*)&wbuf[(c + 1) & 1][0];
#pragma unroll
      for (int i = 0; i < 4; ++i)
        GLL(hn + goffH[i], hb_n + (tid + 256 * i) * 16);
#pragma unroll
      for (int i = 0; i < 3; ++i)
        GLL(wsb4 + goffW[i] + (size_t)(s0 + 2 * (c + 1)) * 128,
            wb_n + (tid + 256 * i) * 16);
    }

    const char* cb = (const char*)&hbuf[c & 1][0];
    const uint4* wl = (const uint4*)&wbuf[c & 1][0];

#pragma unroll
    for (int sl = 0; sl < 2; ++sl) {
      // W fragments from LDS: consecutive-lane b128 -> conflict-free
      FragU W00, W01, W10, W11, W20, W21;
      W00.q = wl[(0 + sl * 2 + 0) * 64 + l];
      W01.q = wl[(0 + sl * 2 + 1) * 64 + l];
      W10.q = wl[(4 + sl * 2 + 0) * 64 + l];
      W11.q = wl[(4 + sl * 2 + 1) * 64 + l];
      W20.q = wl[(8 + sl * 2 + 0) * 64 + l];
      W21.q = wl[(8 + sl * 2 + 1) * 64 + l];

      // h: 8 fp32 via 2 swizzled ds_read_b128
      float4 h0 = *(const float4*)(cb + hrowb + (((sl * 8 + 2 * q + 0) ^ r15) << 4));
      float4 h1 = *(const float4*)(cb + hrowb + (((sl * 8 + 2 * q + 1) ^ r15) << 4));
      float x[8] = {h0.x, h0.y, h0.z, h0.w, h1.x, h1.y, h1.z, h1.w};

      // 3-way truncation split (exact residuals)
      unsigned int u0[8], u1[8], u2[8];
#pragma unroll
      for (int j = 0; j < 8; ++j) {
        unsigned int ux = __float_as_uint(x[j]);
        u0[j] = ux & 0xFFFF0000u;
        float r1 = x[j] - __uint_as_float(u0[j]);
        u1[j] = __float_as_uint(r1) & 0xFFFF0000u;
        float r2 = r1 - __uint_as_float(u1[j]);
        u2[j] = __float_as_uint(r2);
      }
      FragU A0, A1, A2;
      A0.q.x = __builtin_amdgcn_perm(u0[1], u0[0], 0x07060302u);
      A0.q.y = __builtin_amdgcn_perm(u0[3], u0[2], 0x07060302u);
      A0.q.z = __builtin_amdgcn_perm(u0[5], u0[4], 0x07060302u);
      A0.q.w = __builtin_amdgcn_perm(u0[7], u0[6], 0x07060302u);
      A1.q.x = __builtin_amdgcn_perm(u1[1], u1[0], 0x07060302u);
      A1.q.y = __builtin_amdgcn_perm(u1[3], u1[2], 0x07060302u);
      A1.q.z = __builtin_amdgcn_perm(u1[5], u1[4], 0x07060302u);
      A1.q.w = __builtin_amdgcn_perm(u1[7], u1[6], 0x07060302u);
      A2.q.x = __builtin_amdgcn_perm(u2[1], u2[0], 0x07060302u);
      A2.q.y = __builtin_amdgcn_perm(u2[3], u2[2], 0x07060302u);
      A2.q.z = __builtin_amdgcn_perm(u2[5], u2[4], 0x07060302u);
      A2.q.w = __builtin_amdgcn_perm(u2[7], u2[6], 0x07060302u);

      // 6 limb-products per expert-tile into the same fp32 accumulator
      acc0 = __builtin_amdgcn_mfma_f32_16x16x32_bf16(A0.v, W00.v, acc0, 0, 0, 0);
      acc0 = __builtin_amdgcn_mfma_f32_16x16x32_bf16(A0.v, W10.v, acc0, 0, 0, 0);
      acc0 = __builtin_amdgcn_mfma_f32_16x16x32_bf16(A1.v, W00.v, acc0, 0, 0, 0);
      acc0 = __builtin_amdgcn_mfma_f32_16x16x32_bf16(A1.v, W10.v, acc0, 0, 0, 0);
      acc0 = __builtin_amdgcn_mfma_f32_16x16x32_bf16(A0.v, W20.v, acc0, 0, 0, 0);
      acc0 = __builtin_amdgcn_mfma_f32_16x16x32_bf16(A2.v, W00.v, acc0, 0, 0, 0);
      acc1 = __builtin_amdgcn_mfma_f32_16x16x32_bf16(A0.v, W01.v, acc1, 0, 0, 0);
      acc1 = __builtin_amdgcn_mfma_f32_16x16x32_bf16(A0.v, W11.v, acc1, 0, 0, 0);
      acc1 = __builtin_amdgcn_mfma_f32_16x16x32_bf16(A1.v, W01.v, acc1, 0, 0, 0);
      acc1 = __builtin_amdgcn_mfma_f32_16x16x32_bf16(A1.v, W11.v, acc1, 0, 0, 0);
      acc1 = __builtin_amdgcn_mfma_f32_16x16x32_bf16(A0.v, W21.v, acc1, 0, 0, 0);
      acc1 = __builtin_amdgcn_mfma_f32_16x16x32_bf16(A2.v, W01.v, acc1, 0, 0, 0);
    }
    __syncthreads();   // drains vmcnt (next chunk staged) + lgkm; flip buffers
  }

  // ---- write partials (D layout m89: lane l reg r -> D[(l>>4)*4+r][l&15]) --
  float* dst = wsp + ((size_t)kq * T + t0 + wv * 16) * NE;
#pragma unroll
  for (int r = 0; r < 4; ++r) {
    dst[(q * 4 + r) * NE + r15]      = acc0[r];
    dst[(q * 4 + r) * NE + 16 + r15] = acc1[r];
  }

  // ---- last-arrival fused reduce + topk for this token group --------------
  __threadfence();
  __syncthreads();
  if (tid == 0) {
    int old = atomicAdd(&cnt[tg], 1);
    slast = (old == KQ - 1) ? 1 : 0;
  }
  __syncthreads();
  if (slast) {
    __threadfence();
    if (tid < TT) {
      const int tok = t0 + tid;
      float lg[NE];
#pragma unroll
      for (int e = 0; e < NE; e += 4) {
        float4 bb = *(const float4*)(bias + e);
        lg[e] = bb.x; lg[e+1] = bb.y; lg[e+2] = bb.z; lg[e+3] = bb.w;
      }
      for (int qq = 0; qq < KQ; ++qq) {
        const volatile float* p = wsp + ((size_t)qq * T + tok) * NE;
#pragma unroll
        for (int e = 0; e < NE; ++e) lg[e] += p[e];
      }

      float tv[4]; int ti[4];
#pragma unroll
      for (int kk = 0; kk < 4; ++kk) {
        float m = -INFINITY; int mi = 0;
#pragma unroll
        for (int e = 0; e < NE; ++e) {
          bool gt = lg[e] > m;      // strict >: lowest index wins ties (jax)
          m  = gt ? lg[e] : m;
          mi = gt ? e : mi;
        }
        tv[kk] = m; ti[kk] = mi;
#pragma unroll
        for (int e = 0; e < NE; ++e)
          lg[e] = (e == mi) ? -INFINITY : lg[e];
      }

      float e1 = __expf(tv[1] - tv[0]);
      float e2 = __expf(tv[2] - tv[0]);
      float e3 = __expf(tv[3] - tv[0]);
      float inv = 1.0f / (1.0f + e1 + e2 + e3);
      float pr[4] = {inv, e1 * inv, e2 * inv, e3 * inv};

      float* orow = out + (size_t)tok * NE;
#pragma unroll
      for (int g = 0; g < 8; ++g) {
        float4 v;
        float* vp = (float*)&v;
#pragma unroll
        for (int cb2 = 0; cb2 < 4; ++cb2) {
          int e = g * 4 + cb2;
          float xx = 0.f;
          xx = (e == ti[0]) ? pr[0] : xx;
          xx = (e == ti[1]) ? pr[1] : xx;
          xx = (e == ti[2]) ? pr[2] : xx;
          xx = (e == ti[3]) ? pr[3] : xx;
          vp[cb2] = xx;
        }
        *(float4*)(orow + g * 4) = v;
      }
      float* oidx = out + (size_t)T * NE + (size_t)tok * 4;
      float4 iv;
      iv.x = (float)ti[0]; iv.y = (float)ti[1];
      iv.z = (float)ti[2]; iv.w = (float)ti[3];
      *(float4*)oidx = iv;
    }
  }
}

extern "C" void kernel_launch(void* const* d_in, const int* in_sizes, int n_in,
                              void* d_out, int out_size, void* d_ws, size_t ws_size,
                              hipStream_t stream) {
  const float* hs   = (const float*)d_in[0];
  const float* w    = (const float*)d_in[1];
  const float* bias = (const float*)d_in[2];
  float* out        = (float*)d_out;

  const int T   = in_sizes[0] / HID;    // 16384
  const int ntg = T / TT;               // 256

  const size_t per_kq = (size_t)T * NE * 4;
  const int KQ = (ws_size >= WSB_BYTES + 4 * per_kq + 4096) ? 4 : 2;

  unsigned int* wsB = (unsigned int*)d_ws;
  float* wsp        = (float*)((char*)d_ws + WSB_BYTES);
  int* cnt          = (int*)((char*)d_ws + WSB_BYTES + (size_t)KQ * per_kq);

  hipLaunchKernelGGL(wsplit_kernel, dim3(45), dim3(256), 0, stream,
                     w, wsB, cnt, ntg);
  hipLaunchKernelGGL(router_mfma, dim3(ntg * KQ), dim3(THREADS), 0, stream,
                     hs, wsB, wsp, cnt, bias, out, T, KQ, ntg);
}

// Round 13
// 50.332 us; speedup vs baseline: 3.5035x; 3.5035x over previous
//
#include <hip/hip_runtime.h>
#include <math.h>

#define NE 32
#define HID 2880
#define NSTEP 90          // 2880/32 k-steps total
#define TT 64             // tokens per block
#define THREADS 256       // 4 waves; wave wv owns tokens [t0+16*wv, +16)
#define WSB_BYTES (3 * NSTEP * 2 * 64 * 16)   // 552960 B packed W fragments

typedef short bf16x8 __attribute__((ext_vector_type(8)));
typedef float f32x4 __attribute__((ext_vector_type(4)));

union FragU { uint4 q; bf16x8 v; };

// global_load_lds: wave-uniform LDS dest + lane*16; per-lane global src.
#define GLL(gsrc, ldst)                                                        \
  __builtin_amdgcn_global_load_lds(                                            \
      (const __attribute__((address_space(1))) unsigned int*)(gsrc),           \
      (__attribute__((address_space(3))) unsigned int*)(ldst), 16, 0, 0)

// ---------- kernel 0: split W into 3 bf16 limbs packed as B-fragments ------
// Fragment (p, s, t): lane l holds 8 bf16 = W_p[t*16 + (l&15)][s*32 + (l>>4)*8 + j]
__global__ void __launch_bounds__(256) wsplit_kernel(
    const float* __restrict__ w, unsigned int* __restrict__ wsB)
{
  const int gid = blockIdx.x * 256 + threadIdx.x;   // 0..11519
  const int s  = gid >> 7;
  const int tl = (gid >> 6) & 1;
  const int l  = gid & 63;

  const float* src = w + (size_t)(tl * 16 + (l & 15)) * HID + s * 32 + ((l >> 4) * 8);
  float4 xa = *(const float4*)src;
  float4 xb = *(const float4*)(src + 4);
  float x[8] = {xa.x, xa.y, xa.z, xa.w, xb.x, xb.y, xb.z, xb.w};

  unsigned int u0[8], u1[8], u2[8];
#pragma unroll
  for (int j = 0; j < 8; ++j) {
    unsigned int ux = __float_as_uint(x[j]);
    u0[j] = ux & 0xFFFF0000u;                       // limb0 (truncated bf16)
    float r1 = x[j] - __uint_as_float(u0[j]);       // exact
    u1[j] = __float_as_uint(r1) & 0xFFFF0000u;      // limb1
    float r2 = r1 - __uint_as_float(u1[j]);         // exact
    u2[j] = __float_as_uint(r2);                    // limb2 (trunc on pack)
  }

  uint4* dst = (uint4*)wsB;
  uint4 d;
  d.x = __builtin_amdgcn_perm(u0[1], u0[0], 0x07060302u);
  d.y = __builtin_amdgcn_perm(u0[3], u0[2], 0x07060302u);
  d.z = __builtin_amdgcn_perm(u0[5], u0[4], 0x07060302u);
  d.w = __builtin_amdgcn_perm(u0[7], u0[6], 0x07060302u);
  dst[((0 * NSTEP + s) * 2 + tl) * 64 + l] = d;
  d.x = __builtin_amdgcn_perm(u1[1], u1[0], 0x07060302u);
  d.y = __builtin_amdgcn_perm(u1[3], u1[2], 0x07060302u);
  d.z = __builtin_amdgcn_perm(u1[5], u1[4], 0x07060302u);
  d.w = __builtin_amdgcn_perm(u1[7], u1[6], 0x07060302u);
  dst[((1 * NSTEP + s) * 2 + tl) * 64 + l] = d;
  d.x = __builtin_amdgcn_perm(u2[1], u2[0], 0x07060302u);
  d.y = __builtin_amdgcn_perm(u2[3], u2[2], 0x07060302u);
  d.z = __builtin_amdgcn_perm(u2[5], u2[4], 0x07060302u);
  d.w = __builtin_amdgcn_perm(u2[7], u2[6], 0x07060302u);
  dst[((2 * NSTEP + s) * 2 + tl) * 64 + l] = d;
}

// ---------- kernel 1: MFMA GEMM partials, counted-vmcnt pipeline -----------
// h AND W staged via GLL (7 GLL/thread/chunk). Per chunk:
//   barrierA -> stage(c+1) -> vmcnt(7) [retire chunk c only] -> barrierB
//   -> compute c.   Chunk c's loads fly across chunk c-1's entire compute.
__global__ void __launch_bounds__(THREADS) router_mfma(
    const float* __restrict__ hs,         // [T][HID]
    const unsigned int* __restrict__ wsB, // packed W fragments
    float* __restrict__ wsp,              // [KQ][T][NE] fp32 partials
    int T, int KQ, int ntg)
{
  __shared__ float hbuf[2][4096];   // 2 x 16 KB: [64 rows][16 swizzled 16B slots]
  __shared__ float wbuf[2][3072];   // 2 x 12 KB: 12 fragments x 64 lanes x 16 B

  const int tid = threadIdx.x;
  const int wv  = __builtin_amdgcn_readfirstlane(tid >> 6);
  const int l   = tid & 63;
  const int q   = l >> 4;
  const int r15 = l & 15;
  const int tg  = blockIdx.x % ntg;
  const int kq  = blockIdx.x / ntg;
  const int t0  = tg * TT;

  int nsteps, s0;
  if (KQ == 4) { nsteps = (kq == 0) ? 24 : 22; s0 = (kq == 0) ? 0 : (2 + 22 * kq); }
  else         { nsteps = (kq == 0) ? 46 : 44; s0 = (kq == 0) ? 0 : 46; }
  const int nchunk = nsteps >> 1;   // 2 k-steps (64 k) per chunk

  // h staging offsets: phys slot f holds logical slot (f&15)^(row&15) of row f>>4
  int goffH[4];
#pragma unroll
  for (int i = 0; i < 4; ++i) {
    int f = tid + 256 * i;
    int row = f >> 4;
    int G = (f & 15) ^ (row & 15);
    goffH[i] = row * HID + G * 4;   // float offset within chunk
  }
  // W staging offsets (uint4 units, sans k-step term)
  int goffW[3];
#pragma unroll
  for (int i = 0; i < 3; ++i) {
    int j = tid + 256 * i;          // 0..767
    int f = j >> 6, e = j & 63;
    int p = f >> 2, sl = (f >> 1) & 1, t = f & 1;
    goffW[i] = ((p * 2 * NSTEP + sl * 2 + t) * 64 + e);
  }

  const int hrowb = (wv * 16 + r15) * 256;   // row byte base within hbuf

  f32x4 acc0 = {0.f, 0.f, 0.f, 0.f};
  f32x4 acc1 = {0.f, 0.f, 0.f, 0.f};

  const float* hbase = hs + (size_t)t0 * HID + s0 * 32;
  const uint4* wsb4 = (const uint4*)wsB;

#define STAGE(j)                                                               \
  {                                                                            \
    const float* hn = hbase + (j) * 64;                                        \
    char* hb_n = (char*)&hbuf[(j) & 1][0];                                     \
    char* wb_n = (char*)&wbuf[(j) & 1][0];                                     \
    _Pragma("unroll")                                                          \
    for (int i = 0; i < 4; ++i)                                                \
      GLL(hn + goffH[i], hb_n + (tid + 256 * i) * 16);                         \
    _Pragma("unroll")                                                          \
    for (int i = 0; i < 3; ++i)                                                \
      GLL(wsb4 + goffW[i] + (size_t)(s0 + 2 * (j)) * 128,                      \
          wb_n + (tid + 256 * i) * 16);                                        \
  }

  // prologue: stage chunk 0 (7 GLLs outstanding)
  STAGE(0);

#pragma clang loop unroll(disable)
  for (int c = 0; c < nchunk; ++c) {
    // barrier A: all waves finished compute(c-1) -> buf[(c+1)&1] overwrite-safe
    __builtin_amdgcn_s_barrier();

    if (c + 1 < nchunk) {
      STAGE(c + 1);   // chunk c+1 flies across chunk c's compute
      asm volatile("s_waitcnt vmcnt(7)" ::: "memory");   // retire chunk c's 7
    } else {
      asm volatile("s_waitcnt vmcnt(0)" ::: "memory");
    }
    __builtin_amdgcn_sched_barrier(0);
    __builtin_amdgcn_s_barrier();   // barrier B: chunk c visible to all waves
    __builtin_amdgcn_sched_barrier(0);

    const char* cb = (const char*)&hbuf[c & 1][0];
    const uint4* wl = (const uint4*)&wbuf[c & 1][0];

#pragma unroll
    for (int sl = 0; sl < 2; ++sl) {
      // W fragments from LDS: consecutive-lane b128 -> conflict-free
      FragU W00, W01, W10, W11, W20, W21;
      W00.q = wl[(0 + sl * 2 + 0) * 64 + l];
      W01.q = wl[(0 + sl * 2 + 1) * 64 + l];
      W10.q = wl[(4 + sl * 2 + 0) * 64 + l];
      W11.q = wl[(4 + sl * 2 + 1) * 64 + l];
      W20.q = wl[(8 + sl * 2 + 0) * 64 + l];
      W21.q = wl[(8 + sl * 2 + 1) * 64 + l];

      // h: 8 fp32 via 2 swizzled ds_read_b128
      float4 h0 = *(const float4*)(cb + hrowb + (((sl * 8 + 2 * q + 0) ^ r15) << 4));
      float4 h1 = *(const float4*)(cb + hrowb + (((sl * 8 + 2 * q + 1) ^ r15) << 4));
      float x[8] = {h0.x, h0.y, h0.z, h0.w, h1.x, h1.y, h1.z, h1.w};

      // 3-way truncation split (exact residuals)
      unsigned int u0[8], u1[8], u2[8];
#pragma unroll
      for (int j = 0; j < 8; ++j) {
        unsigned int ux = __float_as_uint(x[j]);
        u0[j] = ux & 0xFFFF0000u;
        float r1 = x[j] - __uint_as_float(u0[j]);
        u1[j] = __float_as_uint(r1) & 0xFFFF0000u;
        float r2 = r1 - __uint_as_float(u1[j]);
        u2[j] = __float_as_uint(r2);
      }
      FragU A0, A1, A2;
      A0.q.x = __builtin_amdgcn_perm(u0[1], u0[0], 0x07060302u);
      A0.q.y = __builtin_amdgcn_perm(u0[3], u0[2], 0x07060302u);
      A0.q.z = __builtin_amdgcn_perm(u0[5], u0[4], 0x07060302u);
      A0.q.w = __builtin_amdgcn_perm(u0[7], u0[6], 0x07060302u);
      A1.q.x = __builtin_amdgcn_perm(u1[1], u1[0], 0x07060302u);
      A1.q.y = __builtin_amdgcn_perm(u1[3], u1[2], 0x07060302u);
      A1.q.z = __builtin_amdgcn_perm(u1[5], u1[4], 0x07060302u);
      A1.q.w = __builtin_amdgcn_perm(u1[7], u1[6], 0x07060302u);
      A2.q.x = __builtin_amdgcn_perm(u2[1], u2[0], 0x07060302u);
      A2.q.y = __builtin_amdgcn_perm(u2[3], u2[2], 0x07060302u);
      A2.q.z = __builtin_amdgcn_perm(u2[5], u2[4], 0x07060302u);
      A2.q.w = __builtin_amdgcn_perm(u2[7], u2[6], 0x07060302u);

      // 6 limb-products per expert-tile into the same fp32 accumulator
      acc0 = __builtin_amdgcn_mfma_f32_16x16x32_bf16(A0.v, W00.v, acc0, 0, 0, 0);
      acc0 = __builtin_amdgcn_mfma_f32_16x16x32_bf16(A0.v, W10.v, acc0, 0, 0, 0);
      acc0 = __builtin_amdgcn_mfma_f32_16x16x32_bf16(A1.v, W00.v, acc0, 0, 0, 0);
      acc0 = __builtin_amdgcn_mfma_f32_16x16x32_bf16(A1.v, W10.v, acc0, 0, 0, 0);
      acc0 = __builtin_amdgcn_mfma_f32_16x16x32_bf16(A0.v, W20.v, acc0, 0, 0, 0);
      acc0 = __builtin_amdgcn_mfma_f32_16x16x32_bf16(A2.v, W00.v, acc0, 0, 0, 0);
      acc1 = __builtin_amdgcn_mfma_f32_16x16x32_bf16(A0.v, W01.v, acc1, 0, 0, 0);
      acc1 = __builtin_amdgcn_mfma_f32_16x16x32_bf16(A0.v, W11.v, acc1, 0, 0, 0);
      acc1 = __builtin_amdgcn_mfma_f32_16x16x32_bf16(A1.v, W01.v, acc1, 0, 0, 0);
      acc1 = __builtin_amdgcn_mfma_f32_16x16x32_bf16(A1.v, W11.v, acc1, 0, 0, 0);
      acc1 = __builtin_amdgcn_mfma_f32_16x16x32_bf16(A0.v, W21.v, acc1, 0, 0, 0);
      acc1 = __builtin_amdgcn_mfma_f32_16x16x32_bf16(A2.v, W01.v, acc1, 0, 0, 0);
    }
  }

  // D layout (m89, verified): lane l reg r holds D[(l>>4)*4 + r][l&15]
  float* dst = wsp + ((size_t)kq * T + t0 + wv * 16) * NE;
#pragma unroll
  for (int r = 0; r < 4; ++r) {
    dst[(q * 4 + r) * NE + r15]      = acc0[r];
    dst[(q * 4 + r) * NE + 16 + r15] = acc1[r];
  }
}

// ---------- kernel 2: reduce partials + bias, top-4, softmax, scatter ------
__global__ void __launch_bounds__(256) router_topk(
    const float* __restrict__ wsp, const float* __restrict__ bias,
    float* __restrict__ out, int T, int KQ)
{
  const int tok = blockIdx.x * 256 + threadIdx.x;

  float lg[NE];
#pragma unroll
  for (int e = 0; e < NE; e += 4) {
    float4 bb = *(const float4*)(bias + e);
    lg[e] = bb.x; lg[e+1] = bb.y; lg[e+2] = bb.z; lg[e+3] = bb.w;
  }
  for (int qq = 0; qq < KQ; ++qq) {
    const float* p = wsp + ((size_t)qq * T + tok) * NE;
#pragma unroll
    for (int e = 0; e < NE; e += 4) {
      float4 v = *(const float4*)(p + e);
      lg[e] += v.x; lg[e+1] += v.y; lg[e+2] += v.z; lg[e+3] += v.w;
    }
  }

  float tv[4]; int ti[4];
#pragma unroll
  for (int kk = 0; kk < 4; ++kk) {
    float m = -INFINITY; int mi = 0;
#pragma unroll
    for (int e = 0; e < NE; ++e) {
      bool gt = lg[e] > m;          // strict >: lowest index wins ties (jax)
      m  = gt ? lg[e] : m;
      mi = gt ? e : mi;
    }
    tv[kk] = m; ti[kk] = mi;
#pragma unroll
    for (int e = 0; e < NE; ++e)
      lg[e] = (e == mi) ? -INFINITY : lg[e];
  }

  float e1 = __expf(tv[1] - tv[0]);
  float e2 = __expf(tv[2] - tv[0]);
  float e3 = __expf(tv[3] - tv[0]);
  float inv = 1.0f / (1.0f + e1 + e2 + e3);
  float pr[4] = {inv, e1 * inv, e2 * inv, e3 * inv};

  float* orow = out + (size_t)tok * NE;
#pragma unroll
  for (int g = 0; g < 8; ++g) {
    float4 v;
    float* vp = (float*)&v;
#pragma unroll
    for (int cb = 0; cb < 4; ++cb) {
      int e = g * 4 + cb;
      float xx = 0.f;
      xx = (e == ti[0]) ? pr[0] : xx;
      xx = (e == ti[1]) ? pr[1] : xx;
      xx = (e == ti[2]) ? pr[2] : xx;
      xx = (e == ti[3]) ? pr[3] : xx;
      vp[cb] = xx;
    }
    *(float4*)(orow + g * 4) = v;
  }
  float* oidx = out + (size_t)T * NE + (size_t)tok * 4;
  float4 iv;
  iv.x = (float)ti[0]; iv.y = (float)ti[1]; iv.z = (float)ti[2]; iv.w = (float)ti[3];
  *(float4*)oidx = iv;
}

extern "C" void kernel_launch(void* const* d_in, const int* in_sizes, int n_in,
                              void* d_out, int out_size, void* d_ws, size_t ws_size,
                              hipStream_t stream) {
  const float* hs   = (const float*)d_in[0];
  const float* w    = (const float*)d_in[1];
  const float* bias = (const float*)d_in[2];
  float* out        = (float*)d_out;

  unsigned int* wsB = (unsigned int*)d_ws;
  float* wsp        = (float*)((char*)d_ws + WSB_BYTES);

  const int T   = in_sizes[0] / HID;    // 16384
  const int ntg = T / TT;               // 256

  const size_t per_kq = (size_t)T * NE * 4;
  const int KQ = (ws_size >= WSB_BYTES + 4 * per_kq) ? 4 : 2;

  hipLaunchKernelGGL(wsplit_kernel, dim3(45), dim3(256), 0, stream, w, wsB);
  hipLaunchKernelGGL(router_mfma, dim3(ntg * KQ), dim3(THREADS), 0, stream,
                     hs, wsB, wsp, T, KQ, ntg);
  hipLaunchKernelGGL(router_topk, dim3(T / 256), dim3(256), 0, stream,
                     wsp, bias, out, T, KQ);
}